// Round 10
// baseline (20945.465 us; speedup 1.0000x reference)
//
#include <hip/hip_runtime.h>

#define BB 32      // batch
#define TT 2048    // time steps
#define DD 128     // input dim (layer 1)
#define HH 256     // hidden
#define NTH 1024   // threads per block (16 waves -> 4 waves/SIMD)
#define NRANK 32   // blocks (ranks) per group
#define NGRP 8     // groups = 2 dirs x 4 batch-quads
#define HASHK 2654435761u

typedef float f32x4 __attribute__((ext_vector_type(4)));
typedef unsigned int u32;
typedef u32 u32x2 __attribute__((ext_vector_type(2)));
typedef u32 u32x4 __attribute__((ext_vector_type(4)));

__device__ __forceinline__ float sigm(float x)  { return 1.0f / (1.0f + __expf(-x)); }
__device__ __forceinline__ float tanh_f(float x){ return 1.0f - 2.0f / (__expf(2.0f * x) + 1.0f); }

// Persistent bidirectional scan; 256 blocks = 8 groups x 32 ranks, 1 block/CU.
// W in REGISTERS. h exchange: (h, tag) packets via IC write-through (sc0 sc1),
// tag = step + h_bits*HASHK. Spin issued AFTER the x-dot (r8 lesson: earlier
// polling storms IC). Reduction via red2 LDS round trip (r9 lesson: shfl_xor
// butterfly = 80 LDS-crossbar ops, 3x the red2 cost). This round vs the
// 10.45ms winner: NTH 512->1024 ONLY (4 waves/SIMD, per-thread batch 4->2);
// total FMA/LDS/spin traffic unchanged -- pure TLP doubling (r6->r7 mechanism).
template<int KIN, int LAYER>
__global__ __launch_bounds__(NTH, 1)
void lstm_scan(const float* __restrict__ in_seq, long sb, long st,
               const float* __restrict__ wih_f, const float* __restrict__ whh_f,
               const float* __restrict__ bih_f, const float* __restrict__ bhh_f,
               const float* __restrict__ wih_r, const float* __restrict__ whh_r,
               const float* __restrict__ bih_r, const float* __restrict__ bhh_r,
               float* __restrict__ hseed,      // [NGRP][8][HH]
               float* __restrict__ cseed,      // [NGRP][8][HH]
               u32* __restrict__ hbt,          // [NGRP][2par][256j][8b][2]
               float* __restrict__ out1,       // [TT][BB][2H]
               float* __restrict__ acc,        // [TT][BB]
               const float* __restrict__ fcw,  // [2H]
               int never)
{
    constexpr int KINP = KIN + 4;   // zx stride: odd # of 16B slots
    constexpr int HHP  = HH + 4;    // zh stride: 65 slots, odd
    constexpr int C4   = KIN / 4;
    constexpr int XC   = KIN / 128;                  // x chunks (1 / 4)
    constexpr int NPXI = (8 * C4 + NTH - 1) / NTH;   // px f32x4/thread (1)
    constexpr int RSTR = 36;                         // red2 stride (floats)
    constexpr int PADN = (LAYER == 1) ? 8192 : 5120; // LDS > 80KB: 1 blk/CU

    const int blk  = blockIdx.x;
    const int g    = blk & 7;
    const int rank = blk >> 3;
    const int dir  = g & 1;
    const int bq   = g >> 1;
    const int tid  = threadIdx.x;

    __shared__ __align__(16) float zx[8][KINP];
    __shared__ __align__(16) float zh[8][HHP];
    __shared__ __align__(16) float red2[256 * RSTR];
    __shared__ float gates_s[4][8][9];
    __shared__ float bias_s[32];
    __shared__ float padlds[PADN];
    if (never) padlds[never & (PADN - 1)] = 1.0f;

    const float* wih = dir ? wih_r : wih_f;
    const float* whh = dir ? whh_r : whh_f;
    const float* bih = dir ? bih_r : bih_f;
    const float* bhh = dir ? bhh_r : bhh_f;

    // dot roles: thread = (bh, rg, sl): rows rg*4..+3, b = bh*2..+1, k-slice sl
    const int bh = tid >> 8;        // 0..3
    const int rg = (tid >> 5) & 7;  // 0..7
    const int sl = tid & 31;        // 0..31

    // ---- one-time: W slice -> REGISTERS (bh 0..3 hold identical copies) ----
    f32x4 wx[4][XC], wh[4][2];
    #pragma unroll
    for (int rr = 0; rr < 4; ++rr) {
        const int r = rg * 4 + rr;
        const int grow = (r >> 3) * HH + rank * 8 + (r & 7);
        #pragma unroll
        for (int c = 0; c < XC; ++c)
            wx[rr][c] = *(const f32x4*)(wih + (long)grow * KIN + sl * 4 + 128 * c);
        #pragma unroll
        for (int c = 0; c < 2; ++c)
            wh[rr][c] = *(const f32x4*)(whh + (long)grow * HH + sl * 4 + 128 * c);
    }
    if (tid < 32) {
        const int grow = (tid >> 3) * HH + rank * 8 + (tid & 7);
        bias_s[tid] = bih[grow] + bhh[grow];
    }

    u32* hbt_g = hbt + g * (2 * 256 * 8 * 2);
    float* hs_seed = hseed + g * (8 * HH);
    float* cs_seed = cseed + g * (8 * HH);

    // update roles (tid < 64)
    const int jj2   = tid >> 3;
    const int bl2   = tid & 7;
    const int jglob = rank * 8 + jj2;

    float creg = 0.0f, fcv = 0.0f;
    if (tid < 64 && LAYER == 2) {
        creg = cs_seed[bl2 * HH + jglob];
        fcv  = fcw[dir * HH + jglob];
    }

    // ---- prolog: zx for s=0; seed packets (tag 1) ----
    {
        const int t0 = dir ? (TT - 1) : 0;
        const long tb = (long)t0 * st;
        for (int q = tid; q < 8 * C4; q += NTH) {
            const int bl = q / C4;
            const int k4 = q - bl * C4;
            *(f32x4*)&zx[bl][k4 * 4] =
                *(const f32x4*)(in_seq + (long)(bq * 8 + bl) * sb + tb + k4 * 4);
        }
        if (tid < 64) {
            const float h0 = (LAYER == 1) ? 0.0f : hs_seed[bl2 * HH + jglob];
            const u32 hx = __float_as_uint(h0);
            u32x2 pkt; pkt.x = hx; pkt.y = 1u + hx * HASHK;
            u32* pp = hbt_g + ((0 * 256 + jglob) * 8 + bl2) * 2;
            asm volatile("global_store_dwordx2 %0, %1, off sc0 sc1"
                         :: "v"(pp), "v"(pkt) : "memory");
        }
    }
    __syncthreads();

    for (int s = 0; s < TT; ++s) {
        const int t = dir ? (TT - 1 - s) : s;

        // ---- P0: prefetch x slice for step s+1 (regs; staged in P5) ----
        f32x4 px[NPXI];
        if (s + 1 < TT) {
            const long tb = (long)(dir ? (t - 1) : (t + 1)) * st;
            #pragma unroll
            for (int i = 0; i < NPXI; ++i) {
                const int q = tid + i * NTH;
                if (q < 8 * C4) {
                    const int bl = q / C4;
                    const int k4 = q - bl * C4;
                    px[i] = *(const f32x4*)(in_seq + (long)(bq * 8 + bl) * sb + tb + k4 * 4);
                }
            }
        }

        // ---- P1: x-part of dot (W in regs, z from LDS) ----
        float ac[4][2];
        #pragma unroll
        for (int rr = 0; rr < 4; ++rr)
            #pragma unroll
            for (int b = 0; b < 2; ++b) ac[rr][b] = 0.0f;
        #pragma unroll
        for (int c = 0; c < XC; ++c) {
            f32x4 zv[2];
            #pragma unroll
            for (int b = 0; b < 2; ++b)
                zv[b] = *(const f32x4*)&zx[bh * 2 + b][sl * 4 + 128 * c];
            #pragma unroll
            for (int rr = 0; rr < 4; ++rr) {
                const f32x4 w = wx[rr][c];
                #pragma unroll
                for (int b = 0; b < 2; ++b)
                    ac[rr][b] = fmaf(w.x, zv[b].x, fmaf(w.y, zv[b].y,
                                fmaf(w.z, zv[b].z, fmaf(w.w, zv[b].w, ac[rr][b]))));
            }
        }

        // ---- P2: spin-load tagged h packets (tid<256: thread owns j=tid) ----
        if (tid < 256) {
            const u32 tg = (u32)(s + 1);
            const u32* hp = hbt_g + (((s & 1) * 256 + tid) * 8) * 2;
            u32x4 q0, q1, q2, q3;
            while (true) {
                asm volatile(
                    "global_load_dwordx4 %0, %4, off sc0 sc1\n\t"
                    "global_load_dwordx4 %1, %4, off offset:16 sc0 sc1\n\t"
                    "global_load_dwordx4 %2, %4, off offset:32 sc0 sc1\n\t"
                    "global_load_dwordx4 %3, %4, off offset:48 sc0 sc1\n\t"
                    "s_waitcnt vmcnt(0)"
                    : "=&v"(q0), "=&v"(q1), "=&v"(q2), "=&v"(q3)
                    : "v"(hp) : "memory");
                const bool ok =
                    (q0.y - q0.x * HASHK == tg) && (q0.w - q0.z * HASHK == tg) &&
                    (q1.y - q1.x * HASHK == tg) && (q1.w - q1.z * HASHK == tg) &&
                    (q2.y - q2.x * HASHK == tg) && (q2.w - q2.z * HASHK == tg) &&
                    (q3.y - q3.x * HASHK == tg) && (q3.w - q3.z * HASHK == tg);
                if (ok) break;
                __builtin_amdgcn_s_sleep(1);
            }
            zh[0][tid] = __uint_as_float(q0.x);
            zh[1][tid] = __uint_as_float(q0.z);
            zh[2][tid] = __uint_as_float(q1.x);
            zh[3][tid] = __uint_as_float(q1.z);
            zh[4][tid] = __uint_as_float(q2.x);
            zh[5][tid] = __uint_as_float(q2.z);
            zh[6][tid] = __uint_as_float(q3.x);
            zh[7][tid] = __uint_as_float(q3.z);
        }
        __syncthreads();   // B1: zh ready; zx(s) reads complete

        // ---- P3: h-part of dot + red2 partial writes ----
        #pragma unroll
        for (int c = 0; c < 2; ++c) {
            f32x4 zv[2];
            #pragma unroll
            for (int b = 0; b < 2; ++b)
                zv[b] = *(const f32x4*)&zh[bh * 2 + b][sl * 4 + 128 * c];
            #pragma unroll
            for (int rr = 0; rr < 4; ++rr) {
                const f32x4 w = wh[rr][c];
                #pragma unroll
                for (int b = 0; b < 2; ++b)
                    ac[rr][b] = fmaf(w.x, zv[b].x, fmaf(w.y, zv[b].y,
                                fmaf(w.z, zv[b].z, fmaf(w.w, zv[b].w, ac[rr][b]))));
            }
        }
        #pragma unroll
        for (int rr = 0; rr < 4; ++rr)
            #pragma unroll
            for (int b = 0; b < 2; ++b)
                red2[((rg * 4 + rr) * 8 + bh * 2 + b) * RSTR + sl] = ac[rr][b];
        __syncthreads();   // B2: red2 ready

        // ---- P4: reduce 32 k-slices -> gate pre-activations (tid<256) ----
        if (tid < 256) {
            float sg = bias_s[tid >> 3];
            const f32x4* rp = (const f32x4*)&red2[tid * RSTR];
            #pragma unroll
            for (int q = 0; q < 8; ++q) {
                const f32x4 v = rp[q];
                sg += v.x + v.y + v.z + v.w;
            }
            gates_s[tid >> 6][(tid >> 3) & 7][tid & 7] = sg;
        }
        __syncthreads();   // B3: gates ready

        // ---- P5: cell update, packet store, outputs; stage px -> zx ----
        if (tid < 64) {
            const float gi = gates_s[0][jj2][bl2];
            const float gf = gates_s[1][jj2][bl2];
            const float gg = gates_s[2][jj2][bl2];
            const float go = gates_s[3][jj2][bl2];
            creg = sigm(gf) * creg + sigm(gi) * tanh_f(gg);
            const float hv = sigm(go) * tanh_f(creg);
            if (s + 1 < TT) {
                const u32 hx = __float_as_uint(hv);
                u32x2 pkt; pkt.x = hx; pkt.y = (u32)(s + 2) + hx * HASHK;
                u32* pp = hbt_g + ((((s + 1) & 1) * 256 + jglob) * 8 + bl2) * 2;
                asm volatile("global_store_dwordx2 %0, %1, off sc0 sc1"
                             :: "v"(pp), "v"(pkt) : "memory");
            }
            if (LAYER == 1) {
                out1[(long)t * (BB * 2 * HH) + (bq * 8 + bl2) * (2 * HH) + dir * HH + jglob] = hv;
                if (s == TT - 1) {
                    hs_seed[bl2 * HH + jglob] = hv;
                    cs_seed[bl2 * HH + jglob] = creg;
                }
            } else {
                float val = hv * fcv;
                val += __shfl_down(val, 32, 64);
                val += __shfl_down(val, 16, 64);
                val += __shfl_down(val, 8, 64);
                if (jj2 == 0) atomicAdd(&acc[t * BB + bq * 8 + bl2], val);
            }
        }
        if (s + 1 < TT) {
            #pragma unroll
            for (int i = 0; i < NPXI; ++i) {
                const int q = tid + i * NTH;
                if (q < 8 * C4) {
                    const int bl = q / C4;
                    const int k4 = q - bl * C4;
                    *(f32x4*)&zx[bl][k4 * 4] = px[i];
                }
            }
        }
        __syncthreads();   // B4: loop-end (new zx ready; gates consumed)
    }
}

__global__ void finalize_k(const float* __restrict__ acc, const float* __restrict__ fcb,
                           float* __restrict__ out)
{
    const int i = blockIdx.x * blockDim.x + threadIdx.x;
    if (i < BB * TT) {
        const int b = i >> 11;
        const int t = i & (TT - 1);
        out[i] = tanhf(acc[t * BB + b] + fcb[0]);
    }
}

extern "C" void kernel_launch(void* const* d_in, const int* in_sizes, int n_in,
                              void* d_out, int out_size, void* d_ws, size_t ws_size,
                              hipStream_t stream) {
    const float* x     = (const float*)d_in[0];
    const float* wih1f = (const float*)d_in[1];
    const float* whh1f = (const float*)d_in[2];
    const float* bih1f = (const float*)d_in[3];
    const float* bhh1f = (const float*)d_in[4];
    const float* wih1r = (const float*)d_in[5];
    const float* whh1r = (const float*)d_in[6];
    const float* bih1r = (const float*)d_in[7];
    const float* bhh1r = (const float*)d_in[8];
    const float* wih2f = (const float*)d_in[9];
    const float* whh2f = (const float*)d_in[10];
    const float* bih2f = (const float*)d_in[11];
    const float* bhh2f = (const float*)d_in[12];
    const float* wih2r = (const float*)d_in[13];
    const float* whh2r = (const float*)d_in[14];
    const float* bih2r = (const float*)d_in[15];
    const float* bhh2r = (const float*)d_in[16];
    const float* fcw   = (const float*)d_in[17];
    const float* fcb   = (const float*)d_in[18];

    char* ws = (char*)d_ws;
    size_t off = 0;
    float* acc  = (float*)(ws + off); off += (size_t)TT * BB * 4;                // 256 KB
    u32* hbt1   = (u32*)(ws + off);   off += (size_t)NGRP * 2 * 256 * 8 * 2 * 4; // 256 KB
    u32* hbt2   = (u32*)(ws + off);   off += (size_t)NGRP * 2 * 256 * 8 * 2 * 4; // 256 KB
    float* hseed = (float*)(ws + off); off += (size_t)NGRP * 8 * HH * 4;         // 64 KB
    float* cseed = (float*)(ws + off); off += (size_t)NGRP * 8 * HH * 4;         // 64 KB
    const size_t clear_bytes = off;
    float* out1 = (float*)(ws + off); off += (size_t)TT * BB * 2 * HH * 4;       // 128 MB

    // acc (atomic target), packet buffers (tag space), seeds: zero each launch
    hipMemsetAsync(d_ws, 0, clear_bytes, stream);

    // layer 1: x (B,T,D)
    lstm_scan<DD, 1><<<NGRP * NRANK, NTH, 0, stream>>>(
        x, (long)TT * DD, (long)DD,
        wih1f, whh1f, bih1f, bhh1f, wih1r, whh1r, bih1r, bhh1r,
        hseed, cseed, hbt1, out1, nullptr, nullptr, 0);

    // layer 2: out1 (T,B,2H); seeds = layer-1 finals
    lstm_scan<2 * HH, 2><<<NGRP * NRANK, NTH, 0, stream>>>(
        out1, (long)(2 * HH), (long)(BB * 2 * HH),
        wih2f, whh2f, bih2f, bhh2f, wih2r, whh2r, bih2r, bhh2r,
        hseed, cseed, hbt2, nullptr, acc, fcw, 0);

    finalize_k<<<(BB * TT + 255) / 256, 256, 0, stream>>>(acc, fcb, (float*)d_out);
}

// Round 11
// 18005.228 us; speedup vs baseline: 1.1633x; 1.1633x over previous
//
#include <hip/hip_runtime.h>

#define BB 32      // batch
#define TT 2048    // time steps
#define DD 128     // input dim (layer 1)
#define HH 256     // hidden
#define NTH 512    // threads per block (8 waves -> 2 waves/SIMD; VGPR-bound)
#define NRANK 32   // blocks (ranks) per group
#define NGRP 8     // groups = 2 dirs x 4 batch-quads
#define HASHK 2654435761u

typedef float f32x4 __attribute__((ext_vector_type(4)));
typedef unsigned int u32;
typedef u32 u32x2 __attribute__((ext_vector_type(2)));
typedef u32 u32x4 __attribute__((ext_vector_type(4)));

__device__ __forceinline__ float sigm(float x)  { return 1.0f / (1.0f + __expf(-x)); }
__device__ __forceinline__ float tanh_f(float x){ return 1.0f - 2.0f / (__expf(2.0f * x) + 1.0f); }

// issue the 4 spin loads (8 (h,tag) pairs for j = tid), NO waitcnt
#define SPIN_ISSUE asm volatile( \
    "global_load_dwordx4 %0, %4, off sc0 sc1\n\t" \
    "global_load_dwordx4 %1, %4, off offset:16 sc0 sc1\n\t" \
    "global_load_dwordx4 %2, %4, off offset:32 sc0 sc1\n\t" \
    "global_load_dwordx4 %3, %4, off offset:48 sc0 sc1" \
    : "=&v"(q0), "=&v"(q1), "=&v"(q2), "=&v"(q3) : "v"(hp) : "memory")

// wait with q-register ties (data dependency pins the tag check after the wait)
#define WAIT_TIED(N) asm volatile("s_waitcnt vmcnt(" #N ")" \
    : "+v"(q0), "+v"(q1), "+v"(q2), "+v"(q3) :: "memory")

// Persistent bidirectional scan; 256 blocks = 8 groups x 32 ranks, 1 block/CU.
// W in REGISTERS; x-operands now ALSO in registers (global->reg direct, no zx
// LDS round trip -- the 8-way rg re-read duplication is absorbed by the 32KB
// vector L1; per-step x slice = 16KB). h exchange: (h, tag) packets via IC
// write-through (sc0 sc1), tag = step + h_bits*HASHK. Spin issued AFTER the
// x-dot (r8 lesson); spin's FIRST wait is vmcnt(4*XC) so it does NOT drain
// the just-issued x(s+1) loads (in-order vmcnt; retries use vmcnt(0); a
// wrong count only garbles q regs -> tag check fails -> retry => safe).
template<int KIN, int LAYER>
__global__ __launch_bounds__(NTH, 1)
void lstm_scan(const float* __restrict__ in_seq, long sb, long st,
               const float* __restrict__ wih_f, const float* __restrict__ whh_f,
               const float* __restrict__ bih_f, const float* __restrict__ bhh_f,
               const float* __restrict__ wih_r, const float* __restrict__ whh_r,
               const float* __restrict__ bih_r, const float* __restrict__ bhh_r,
               float* __restrict__ hseed,      // [NGRP][8][HH]
               float* __restrict__ cseed,      // [NGRP][8][HH]
               u32* __restrict__ hbt,          // [NGRP][2par][256j][8b][2]
               float* __restrict__ out1,       // [TT][BB][2H]
               float* __restrict__ acc,        // [TT][BB]
               const float* __restrict__ fcw,  // [2H]
               int never)
{
    constexpr int HHP  = HH + 4;    // zh stride: 65 16B-slots, odd
    constexpr int XC   = KIN / 128; // x chunks per thread (1 / 4)
    constexpr int RSTR = 36;        // red2 stride (floats)
    constexpr int PADN = 9216;      // LDS total ~83.3KB > 80KB: 1 block/CU

    const int blk  = blockIdx.x;
    const int g    = blk & 7;
    const int rank = blk >> 3;
    const int dir  = g & 1;
    const int bq   = g >> 1;
    const int tid  = threadIdx.x;

    __shared__ __align__(16) float zh[8][HHP];
    __shared__ __align__(16) float red2[256 * RSTR];
    __shared__ float gates_s[4][8][9];
    __shared__ float bias_s[32];
    __shared__ float padlds[PADN];
    if (never) padlds[never & (PADN - 1)] = 1.0f;

    const float* wih = dir ? wih_r : wih_f;
    const float* whh = dir ? whh_r : whh_f;
    const float* bih = dir ? bih_r : bih_f;
    const float* bhh = dir ? bhh_r : bhh_f;

    // dot roles: thread = (bh, rg, sl): rows rg*4..+3, b = bh*4..+3, k-slice sl
    const int bh = tid >> 8;        // 0/1
    const int rg = (tid >> 5) & 7;  // 0..7
    const int sl = tid & 31;        // 0..31

    // ---- one-time: W slice -> REGISTERS ----
    f32x4 wx[4][XC], wh[4][2];
    #pragma unroll
    for (int rr = 0; rr < 4; ++rr) {
        const int r = rg * 4 + rr;
        const int grow = (r >> 3) * HH + rank * 8 + (r & 7);
        #pragma unroll
        for (int c = 0; c < XC; ++c)
            wx[rr][c] = *(const f32x4*)(wih + (long)grow * KIN + sl * 4 + 128 * c);
        #pragma unroll
        for (int c = 0; c < 2; ++c)
            wh[rr][c] = *(const f32x4*)(whh + (long)grow * HH + sl * 4 + 128 * c);
    }
    if (tid < 32) {
        const int grow = (tid >> 3) * HH + rank * 8 + (tid & 7);
        bias_s[tid] = bih[grow] + bhh[grow];
    }

    u32* hbt_g = hbt + g * (2 * 256 * 8 * 2);
    float* hs_seed = hseed + g * (8 * HH);
    float* cs_seed = cseed + g * (8 * HH);

    // update roles (tid < 64)
    const int jj2   = tid >> 3;
    const int bl2   = tid & 7;
    const int jglob = rank * 8 + jj2;

    float creg = 0.0f, fcv = 0.0f;
    if (tid < 64 && LAYER == 2) {
        creg = cs_seed[bl2 * HH + jglob];
        fcv  = fcw[dir * HH + jglob];
    }

    // ---- prolog: x(0) operands -> registers; seed packets (tag 1) ----
    f32x4 xr[4][XC];
    {
        const int t0 = dir ? (TT - 1) : 0;
        const long tb = (long)t0 * st;
        #pragma unroll
        for (int bi = 0; bi < 4; ++bi)
            #pragma unroll
            for (int c = 0; c < XC; ++c)
                xr[bi][c] = *(const f32x4*)(in_seq +
                    (long)(bq * 8 + bh * 4 + bi) * sb + tb + sl * 4 + 128 * c);
        if (tid < 64) {
            const float h0 = (LAYER == 1) ? 0.0f : hs_seed[bl2 * HH + jglob];
            const u32 hx = __float_as_uint(h0);
            u32x2 pkt; pkt.x = hx; pkt.y = 1u + hx * HASHK;
            u32* pp = hbt_g + ((0 * 256 + jglob) * 8 + bl2) * 2;
            asm volatile("global_store_dwordx2 %0, %1, off sc0 sc1"
                         :: "v"(pp), "v"(pkt) : "memory");
        }
    }
    __syncthreads();

    for (int s = 0; s < TT; ++s) {
        const int t = dir ? (TT - 1 - s) : s;

        // ---- P1: x-part of dot (W and x both in registers; zero LDS) ----
        float ac[4][4];
        #pragma unroll
        for (int rr = 0; rr < 4; ++rr)
            #pragma unroll
            for (int b = 0; b < 4; ++b) ac[rr][b] = 0.0f;
        #pragma unroll
        for (int c = 0; c < XC; ++c) {
            #pragma unroll
            for (int rr = 0; rr < 4; ++rr) {
                const f32x4 w = wx[rr][c];
                #pragma unroll
                for (int b = 0; b < 4; ++b) {
                    const f32x4 zv = xr[b][c];
                    ac[rr][b] = fmaf(w.x, zv.x, fmaf(w.y, zv.y,
                                fmaf(w.z, zv.z, fmaf(w.w, zv.w, ac[rr][b]))));
                }
            }
        }

        // ---- P2: spin issue -> x(s+1) issue -> wait(excl. x) -> tag check ----
        const u32 tg = (u32)(s + 1);
        const u32* hp = hbt_g + (((s & 1) * 256 + tid) * 8) * 2;
        u32x4 q0, q1, q2, q3;
        if (tid < 256) { SPIN_ISSUE; }
        if (s + 1 < TT) {   // x operands for step s+1 overwrite xr (last read was P1)
            const long tb = (long)(dir ? (t - 1) : (t + 1)) * st;
            #pragma unroll
            for (int bi = 0; bi < 4; ++bi)
                #pragma unroll
                for (int c = 0; c < XC; ++c)
                    xr[bi][c] = *(const f32x4*)(in_seq +
                        (long)(bq * 8 + bh * 4 + bi) * sb + tb + sl * 4 + 128 * c);
        }
        if (tid < 256) {
            if (s + 1 < TT) {
                if constexpr (XC == 1) { WAIT_TIED(4); } else { WAIT_TIED(16); }
            } else {
                WAIT_TIED(0);
            }
            while (true) {
                const bool ok =
                    (q0.y - q0.x * HASHK == tg) && (q0.w - q0.z * HASHK == tg) &&
                    (q1.y - q1.x * HASHK == tg) && (q1.w - q1.z * HASHK == tg) &&
                    (q2.y - q2.x * HASHK == tg) && (q2.w - q2.z * HASHK == tg) &&
                    (q3.y - q3.x * HASHK == tg) && (q3.w - q3.z * HASHK == tg);
                if (ok) break;
                __builtin_amdgcn_s_sleep(1);
                SPIN_ISSUE;
                WAIT_TIED(0);
            }
            zh[0][tid] = __uint_as_float(q0.x);
            zh[1][tid] = __uint_as_float(q0.z);
            zh[2][tid] = __uint_as_float(q1.x);
            zh[3][tid] = __uint_as_float(q1.z);
            zh[4][tid] = __uint_as_float(q2.x);
            zh[5][tid] = __uint_as_float(q2.z);
            zh[6][tid] = __uint_as_float(q3.x);
            zh[7][tid] = __uint_as_float(q3.z);
        }
        __syncthreads();   // B1: zh ready

        // ---- P3: h-part of dot + red2 partial writes ----
        #pragma unroll
        for (int c = 0; c < 2; ++c) {
            f32x4 zv[4];
            #pragma unroll
            for (int b = 0; b < 4; ++b)
                zv[b] = *(const f32x4*)&zh[bh * 4 + b][sl * 4 + 128 * c];
            #pragma unroll
            for (int rr = 0; rr < 4; ++rr) {
                const f32x4 w = wh[rr][c];
                #pragma unroll
                for (int b = 0; b < 4; ++b)
                    ac[rr][b] = fmaf(w.x, zv[b].x, fmaf(w.y, zv[b].y,
                                fmaf(w.z, zv[b].z, fmaf(w.w, zv[b].w, ac[rr][b]))));
            }
        }
        #pragma unroll
        for (int rr = 0; rr < 4; ++rr)
            #pragma unroll
            for (int b = 0; b < 4; ++b)
                red2[((rg * 4 + rr) * 8 + bh * 4 + b) * RSTR + sl] = ac[rr][b];
        __syncthreads();   // B2: red2 ready

        // ---- P4: reduce 32 k-slices -> gate pre-activations (tid<256) ----
        if (tid < 256) {
            float sg = bias_s[tid >> 3];
            const f32x4* rp = (const f32x4*)&red2[tid * RSTR];
            #pragma unroll
            for (int q = 0; q < 8; ++q) {
                const f32x4 v = rp[q];
                sg += v.x + v.y + v.z + v.w;
            }
            gates_s[tid >> 6][(tid >> 3) & 7][tid & 7] = sg;
        }
        __syncthreads();   // B3: gates ready

        // ---- P5: cell update; packet store FIRST, then outputs ----
        // (no trailing barrier: spin(s+1) gates cross-rank by transitivity;
        //  intra-block LDS hazards all covered by B1/B2/B3)
        if (tid < 64) {
            const float gi = gates_s[0][jj2][bl2];
            const float gf = gates_s[1][jj2][bl2];
            const float gg = gates_s[2][jj2][bl2];
            const float go = gates_s[3][jj2][bl2];
            creg = sigm(gf) * creg + sigm(gi) * tanh_f(gg);
            const float hv = sigm(go) * tanh_f(creg);
            if (s + 1 < TT) {
                const u32 hx = __float_as_uint(hv);
                u32x2 pkt; pkt.x = hx; pkt.y = (u32)(s + 2) + hx * HASHK;
                u32* pp = hbt_g + ((((s + 1) & 1) * 256 + jglob) * 8 + bl2) * 2;
                asm volatile("global_store_dwordx2 %0, %1, off sc0 sc1"
                             :: "v"(pp), "v"(pkt) : "memory");
            }
            if (LAYER == 1) {
                out1[(long)t * (BB * 2 * HH) + (bq * 8 + bl2) * (2 * HH) + dir * HH + jglob] = hv;
                if (s == TT - 1) {
                    hs_seed[bl2 * HH + jglob] = hv;
                    cs_seed[bl2 * HH + jglob] = creg;
                }
            } else {
                float val = hv * fcv;
                val += __shfl_down(val, 32, 64);
                val += __shfl_down(val, 16, 64);
                val += __shfl_down(val, 8, 64);
                if (jj2 == 0) atomicAdd(&acc[t * BB + bq * 8 + bl2], val);
            }
        }
    }
}

__global__ void finalize_k(const float* __restrict__ acc, const float* __restrict__ fcb,
                           float* __restrict__ out)
{
    const int i = blockIdx.x * blockDim.x + threadIdx.x;
    if (i < BB * TT) {
        const int b = i >> 11;
        const int t = i & (TT - 1);
        out[i] = tanhf(acc[t * BB + b] + fcb[0]);
    }
}

extern "C" void kernel_launch(void* const* d_in, const int* in_sizes, int n_in,
                              void* d_out, int out_size, void* d_ws, size_t ws_size,
                              hipStream_t stream) {
    const float* x     = (const float*)d_in[0];
    const float* wih1f = (const float*)d_in[1];
    const float* whh1f = (const float*)d_in[2];
    const float* bih1f = (const float*)d_in[3];
    const float* bhh1f = (const float*)d_in[4];
    const float* wih1r = (const float*)d_in[5];
    const float* whh1r = (const float*)d_in[6];
    const float* bih1r = (const float*)d_in[7];
    const float* bhh1r = (const float*)d_in[8];
    const float* wih2f = (const float*)d_in[9];
    const float* whh2f = (const float*)d_in[10];
    const float* bih2f = (const float*)d_in[11];
    const float* bhh2f = (const float*)d_in[12];
    const float* wih2r = (const float*)d_in[13];
    const float* whh2r = (const float*)d_in[14];
    const float* bih2r = (const float*)d_in[15];
    const float* bhh2r = (const float*)d_in[16];
    const float* fcw   = (const float*)d_in[17];
    const float* fcb   = (const float*)d_in[18];

    char* ws = (char*)d_ws;
    size_t off = 0;
    float* acc  = (float*)(ws + off); off += (size_t)TT * BB * 4;                // 256 KB
    u32* hbt1   = (u32*)(ws + off);   off += (size_t)NGRP * 2 * 256 * 8 * 2 * 4; // 256 KB
    u32* hbt2   = (u32*)(ws + off);   off += (size_t)NGRP * 2 * 256 * 8 * 2 * 4; // 256 KB
    float* hseed = (float*)(ws + off); off += (size_t)NGRP * 8 * HH * 4;         // 64 KB
    float* cseed = (float*)(ws + off); off += (size_t)NGRP * 8 * HH * 4;         // 64 KB
    const size_t clear_bytes = off;
    float* out1 = (float*)(ws + off); off += (size_t)TT * BB * 2 * HH * 4;       // 128 MB

    // acc (atomic target), packet buffers (tag space), seeds: zero each launch
    hipMemsetAsync(d_ws, 0, clear_bytes, stream);

    // layer 1: x (B,T,D)
    lstm_scan<DD, 1><<<NGRP * NRANK, NTH, 0, stream>>>(
        x, (long)TT * DD, (long)DD,
        wih1f, whh1f, bih1f, bhh1f, wih1r, whh1r, bih1r, bhh1r,
        hseed, cseed, hbt1, out1, nullptr, nullptr, 0);

    // layer 2: out1 (T,B,2H); seeds = layer-1 finals
    lstm_scan<2 * HH, 2><<<NGRP * NRANK, NTH, 0, stream>>>(
        out1, (long)(2 * HH), (long)(BB * 2 * HH),
        wih2f, whh2f, bih2f, bhh2f, wih2r, whh2r, bih2r, bhh2r,
        hseed, cseed, hbt2, nullptr, acc, fcw, 0);

    finalize_k<<<(BB * TT + 255) / 256, 256, 0, stream>>>(acc, fcb, (float*)d_out);
}

// Round 12
// 15091.591 us; speedup vs baseline: 1.3879x; 1.1931x over previous
//
#include <hip/hip_runtime.h>

#define BB 32      // batch
#define TT 2048    // time steps
#define DD 128     // input dim (layer 1)
#define HH 256     // hidden
#define NTH 512    // threads per block (8 waves -> 2 waves/SIMD; VGPR-bound)
#define NRANK 32   // blocks (ranks) per group
#define NGRP 8     // groups = 2 dirs x 4 batch-quads
#define HASHK 2654435761u

typedef float f32x4 __attribute__((ext_vector_type(4)));
typedef unsigned int u32;
typedef u32 u32x2 __attribute__((ext_vector_type(2)));
typedef u32 u32x4 __attribute__((ext_vector_type(4)));

__device__ __forceinline__ float sigm(float x)  { return 1.0f / (1.0f + __expf(-x)); }
__device__ __forceinline__ float tanh_f(float x){ return 1.0f - 2.0f / (__expf(2.0f * x) + 1.0f); }

// issue the 4 spin loads (8 (h,tag) pairs for j = tid), NO waitcnt
#define SPIN_ISSUE asm volatile( \
    "global_load_dwordx4 %0, %4, off sc0 sc1\n\t" \
    "global_load_dwordx4 %1, %4, off offset:16 sc0 sc1\n\t" \
    "global_load_dwordx4 %2, %4, off offset:32 sc0 sc1\n\t" \
    "global_load_dwordx4 %3, %4, off offset:48 sc0 sc1" \
    : "=&v"(q0), "=&v"(q1), "=&v"(q2), "=&v"(q3) : "v"(hp) : "memory")

// wait with q-register ties (data dependency pins the tag check after the wait)
#define WAIT_TIED(N) asm volatile("s_waitcnt vmcnt(" #N ")" \
    : "+v"(q0), "+v"(q1), "+v"(q2), "+v"(q3) :: "memory")

// Persistent bidirectional scan; 256 blocks = 8 groups x 32 ranks, 1 block/CU.
// == The 10.45ms r7 winner, with ONE change: px prefetch is issued AFTER the
// spin loads, and the spin's first wait is a counted vmcnt(NPXI) so in-order
// vmcnt retirement completes exactly the 4 spin loads while px stays in
// flight (r7 issued px first, so its vmcnt(0) drained px on the critical
// path). Retries use vmcnt(0) -- px is done by then; a wrong count only
// garbles q regs -> tag check fails -> retry => hang-safe. W in REGISTERS
// (96 VGPR, the r10/r11 lesson: no more register residents fit at NTH=512).
template<int KIN, int LAYER>
__global__ __launch_bounds__(NTH, 1)
void lstm_scan(const float* __restrict__ in_seq, long sb, long st,
               const float* __restrict__ wih_f, const float* __restrict__ whh_f,
               const float* __restrict__ bih_f, const float* __restrict__ bhh_f,
               const float* __restrict__ wih_r, const float* __restrict__ whh_r,
               const float* __restrict__ bih_r, const float* __restrict__ bhh_r,
               float* __restrict__ hseed,      // [NGRP][8][HH]
               float* __restrict__ cseed,      // [NGRP][8][HH]
               u32* __restrict__ hbt,          // [NGRP][2par][256j][8b][2]
               float* __restrict__ out1,       // [TT][BB][2H]
               float* __restrict__ acc,        // [TT][BB]
               const float* __restrict__ fcw,  // [2H]
               int never)
{
    constexpr int KINP = KIN + 4;   // zx stride: odd # of 16B slots
    constexpr int HHP  = HH + 4;    // zh stride: 65 slots, odd
    constexpr int C4   = KIN / 4;
    constexpr int XC   = KIN / 128;                  // x chunks (1 / 4)
    constexpr int NPXI = (8 * C4 + NTH - 1) / NTH;   // px f32x4/thread (1 / 2)
    constexpr int RSTR = 36;                         // red2 stride (floats)
    constexpr int PADN = (LAYER == 1) ? 8192 : 5120; // LDS > 80KB: 1 blk/CU

    const int blk  = blockIdx.x;
    const int g    = blk & 7;
    const int rank = blk >> 3;
    const int dir  = g & 1;
    const int bq   = g >> 1;
    const int tid  = threadIdx.x;

    __shared__ __align__(16) float zx[8][KINP];
    __shared__ __align__(16) float zh[8][HHP];
    __shared__ __align__(16) float red2[256 * RSTR];
    __shared__ float gates_s[4][8][9];
    __shared__ float bias_s[32];
    __shared__ float padlds[PADN];
    if (never) padlds[never & (PADN - 1)] = 1.0f;

    const float* wih = dir ? wih_r : wih_f;
    const float* whh = dir ? whh_r : whh_f;
    const float* bih = dir ? bih_r : bih_f;
    const float* bhh = dir ? bhh_r : bhh_f;

    // dot roles: thread = (bh, rg, sl): rows rg*4..+3, b = bh*4..+3, k-slice sl
    const int bh = tid >> 8;        // 0/1
    const int rg = (tid >> 5) & 7;  // 0..7
    const int sl = tid & 31;        // 0..31

    // ---- one-time: W slice -> REGISTERS (bh=0/1 hold identical copies) ----
    f32x4 wx[4][XC], wh[4][2];
    #pragma unroll
    for (int rr = 0; rr < 4; ++rr) {
        const int r = rg * 4 + rr;
        const int grow = (r >> 3) * HH + rank * 8 + (r & 7);
        #pragma unroll
        for (int c = 0; c < XC; ++c)
            wx[rr][c] = *(const f32x4*)(wih + (long)grow * KIN + sl * 4 + 128 * c);
        #pragma unroll
        for (int c = 0; c < 2; ++c)
            wh[rr][c] = *(const f32x4*)(whh + (long)grow * HH + sl * 4 + 128 * c);
    }
    if (tid < 32) {
        const int grow = (tid >> 3) * HH + rank * 8 + (tid & 7);
        bias_s[tid] = bih[grow] + bhh[grow];
    }

    u32* hbt_g = hbt + g * (2 * 256 * 8 * 2);
    float* hs_seed = hseed + g * (8 * HH);
    float* cs_seed = cseed + g * (8 * HH);

    // update roles (tid < 64)
    const int jj2   = tid >> 3;
    const int bl2   = tid & 7;
    const int jglob = rank * 8 + jj2;

    float creg = 0.0f, fcv = 0.0f;
    if (tid < 64 && LAYER == 2) {
        creg = cs_seed[bl2 * HH + jglob];
        fcv  = fcw[dir * HH + jglob];
    }

    // ---- prolog: zx for s=0; seed packets (tag 1) ----
    {
        const int t0 = dir ? (TT - 1) : 0;
        const long tb = (long)t0 * st;
        for (int q = tid; q < 8 * C4; q += NTH) {
            const int bl = q / C4;
            const int k4 = q - bl * C4;
            *(f32x4*)&zx[bl][k4 * 4] =
                *(const f32x4*)(in_seq + (long)(bq * 8 + bl) * sb + tb + k4 * 4);
        }
        if (tid < 64) {
            const float h0 = (LAYER == 1) ? 0.0f : hs_seed[bl2 * HH + jglob];
            const u32 hx = __float_as_uint(h0);
            u32x2 pkt; pkt.x = hx; pkt.y = 1u + hx * HASHK;
            u32* pp = hbt_g + ((0 * 256 + jglob) * 8 + bl2) * 2;
            asm volatile("global_store_dwordx2 %0, %1, off sc0 sc1"
                         :: "v"(pp), "v"(pkt) : "memory");
        }
    }
    __syncthreads();

    for (int s = 0; s < TT; ++s) {
        const int t = dir ? (TT - 1 - s) : s;

        // ---- P1: x-part of dot (W in regs, z from LDS) ----
        float ac[4][4];
        #pragma unroll
        for (int rr = 0; rr < 4; ++rr)
            #pragma unroll
            for (int b = 0; b < 4; ++b) ac[rr][b] = 0.0f;
        #pragma unroll
        for (int c = 0; c < XC; ++c) {
            f32x4 zv[4];
            #pragma unroll
            for (int b = 0; b < 4; ++b)
                zv[b] = *(const f32x4*)&zx[bh * 4 + b][sl * 4 + 128 * c];
            #pragma unroll
            for (int rr = 0; rr < 4; ++rr) {
                const f32x4 w = wx[rr][c];
                #pragma unroll
                for (int b = 0; b < 4; ++b)
                    ac[rr][b] = fmaf(w.x, zv[b].x, fmaf(w.y, zv[b].y,
                                fmaf(w.z, zv[b].z, fmaf(w.w, zv[b].w, ac[rr][b]))));
            }
        }

        // ---- P2: spin issue -> px issue -> counted wait -> tag check ----
        const u32 tg = (u32)(s + 1);
        const u32* hp = hbt_g + (((s & 1) * 256 + tid) * 8) * 2;
        u32x4 q0, q1, q2, q3;
        if (tid < 256) { SPIN_ISSUE; }
        f32x4 px[NPXI];
        if (s + 1 < TT) {   // px issued AFTER spin loads: counted wait excludes it
            const long tb = (long)(dir ? (t - 1) : (t + 1)) * st;
            #pragma unroll
            for (int i = 0; i < NPXI; ++i) {
                const int q = tid + i * NTH;
                if (q < 8 * C4) {
                    const int bl = q / C4;
                    const int k4 = q - bl * C4;
                    px[i] = *(const f32x4*)(in_seq + (long)(bq * 8 + bl) * sb + tb + k4 * 4);
                }
            }
        }
        if (tid < 256) {
            if (s + 1 < TT) {
                if constexpr (NPXI == 1) { WAIT_TIED(1); } else { WAIT_TIED(2); }
            } else {
                WAIT_TIED(0);
            }
            while (true) {
                const bool ok =
                    (q0.y - q0.x * HASHK == tg) && (q0.w - q0.z * HASHK == tg) &&
                    (q1.y - q1.x * HASHK == tg) && (q1.w - q1.z * HASHK == tg) &&
                    (q2.y - q2.x * HASHK == tg) && (q2.w - q2.z * HASHK == tg) &&
                    (q3.y - q3.x * HASHK == tg) && (q3.w - q3.z * HASHK == tg);
                if (ok) break;
                __builtin_amdgcn_s_sleep(1);
                SPIN_ISSUE;
                WAIT_TIED(0);
            }
            zh[0][tid] = __uint_as_float(q0.x);
            zh[1][tid] = __uint_as_float(q0.z);
            zh[2][tid] = __uint_as_float(q1.x);
            zh[3][tid] = __uint_as_float(q1.z);
            zh[4][tid] = __uint_as_float(q2.x);
            zh[5][tid] = __uint_as_float(q2.z);
            zh[6][tid] = __uint_as_float(q3.x);
            zh[7][tid] = __uint_as_float(q3.z);
        }
        __syncthreads();   // B1: zh ready; zx(s) reads complete

        // ---- P3: h-part of dot + red2 partial writes; stage px -> zx ----
        #pragma unroll
        for (int c = 0; c < 2; ++c) {
            f32x4 zv[4];
            #pragma unroll
            for (int b = 0; b < 4; ++b)
                zv[b] = *(const f32x4*)&zh[bh * 4 + b][sl * 4 + 128 * c];
            #pragma unroll
            for (int rr = 0; rr < 4; ++rr) {
                const f32x4 w = wh[rr][c];
                #pragma unroll
                for (int b = 0; b < 4; ++b)
                    ac[rr][b] = fmaf(w.x, zv[b].x, fmaf(w.y, zv[b].y,
                                fmaf(w.z, zv[b].z, fmaf(w.w, zv[b].w, ac[rr][b]))));
            }
        }
        #pragma unroll
        for (int rr = 0; rr < 4; ++rr)
            #pragma unroll
            for (int b = 0; b < 4; ++b)
                red2[((rg * 4 + rr) * 8 + bh * 4 + b) * RSTR + sl] = ac[rr][b];
        if (s + 1 < TT) {
            #pragma unroll
            for (int i = 0; i < NPXI; ++i) {
                const int q = tid + i * NTH;
                if (q < 8 * C4) {
                    const int bl = q / C4;
                    const int k4 = q - bl * C4;
                    *(f32x4*)&zx[bl][k4 * 4] = px[i];
                }
            }
        }
        __syncthreads();   // B2: red2 + new zx ready

        // ---- P4: reduce 32 k-slices -> gate pre-activations (tid<256) ----
        if (tid < 256) {
            float sg = bias_s[tid >> 3];
            const f32x4* rp = (const f32x4*)&red2[tid * RSTR];
            #pragma unroll
            for (int q = 0; q < 8; ++q) {
                const f32x4 v = rp[q];
                sg += v.x + v.y + v.z + v.w;
            }
            gates_s[tid >> 6][(tid >> 3) & 7][tid & 7] = sg;
        }
        __syncthreads();   // B3: gates ready

        // ---- P5: cell update; packet store FIRST, then outputs ----
        // (no trailing barrier: spin(s+1) gates cross-rank by transitivity;
        //  intra-block LDS hazards all covered by B1/B2/B3)
        if (tid < 64) {
            const float gi = gates_s[0][jj2][bl2];
            const float gf = gates_s[1][jj2][bl2];
            const float gg = gates_s[2][jj2][bl2];
            const float go = gates_s[3][jj2][bl2];
            creg = sigm(gf) * creg + sigm(gi) * tanh_f(gg);
            const float hv = sigm(go) * tanh_f(creg);
            if (s + 1 < TT) {
                const u32 hx = __float_as_uint(hv);
                u32x2 pkt; pkt.x = hx; pkt.y = (u32)(s + 2) + hx * HASHK;
                u32* pp = hbt_g + ((((s + 1) & 1) * 256 + jglob) * 8 + bl2) * 2;
                asm volatile("global_store_dwordx2 %0, %1, off sc0 sc1"
                             :: "v"(pp), "v"(pkt) : "memory");
            }
            if (LAYER == 1) {
                out1[(long)t * (BB * 2 * HH) + (bq * 8 + bl2) * (2 * HH) + dir * HH + jglob] = hv;
                if (s == TT - 1) {
                    hs_seed[bl2 * HH + jglob] = hv;
                    cs_seed[bl2 * HH + jglob] = creg;
                }
            } else {
                float val = hv * fcv;
                val += __shfl_down(val, 32, 64);
                val += __shfl_down(val, 16, 64);
                val += __shfl_down(val, 8, 64);
                if (jj2 == 0) atomicAdd(&acc[t * BB + bq * 8 + bl2], val);
            }
        }
    }
}

__global__ void finalize_k(const float* __restrict__ acc, const float* __restrict__ fcb,
                           float* __restrict__ out)
{
    const int i = blockIdx.x * blockDim.x + threadIdx.x;
    if (i < BB * TT) {
        const int b = i >> 11;
        const int t = i & (TT - 1);
        out[i] = tanhf(acc[t * BB + b] + fcb[0]);
    }
}

extern "C" void kernel_launch(void* const* d_in, const int* in_sizes, int n_in,
                              void* d_out, int out_size, void* d_ws, size_t ws_size,
                              hipStream_t stream) {
    const float* x     = (const float*)d_in[0];
    const float* wih1f = (const float*)d_in[1];
    const float* whh1f = (const float*)d_in[2];
    const float* bih1f = (const float*)d_in[3];
    const float* bhh1f = (const float*)d_in[4];
    const float* wih1r = (const float*)d_in[5];
    const float* whh1r = (const float*)d_in[6];
    const float* bih1r = (const float*)d_in[7];
    const float* bhh1r = (const float*)d_in[8];
    const float* wih2f = (const float*)d_in[9];
    const float* whh2f = (const float*)d_in[10];
    const float* bih2f = (const float*)d_in[11];
    const float* bhh2f = (const float*)d_in[12];
    const float* wih2r = (const float*)d_in[13];
    const float* whh2r = (const float*)d_in[14];
    const float* bih2r = (const float*)d_in[15];
    const float* bhh2r = (const float*)d_in[16];
    const float* fcw   = (const float*)d_in[17];
    const float* fcb   = (const float*)d_in[18];

    char* ws = (char*)d_ws;
    size_t off = 0;
    float* acc  = (float*)(ws + off); off += (size_t)TT * BB * 4;                // 256 KB
    u32* hbt1   = (u32*)(ws + off);   off += (size_t)NGRP * 2 * 256 * 8 * 2 * 4; // 256 KB
    u32* hbt2   = (u32*)(ws + off);   off += (size_t)NGRP * 2 * 256 * 8 * 2 * 4; // 256 KB
    float* hseed = (float*)(ws + off); off += (size_t)NGRP * 8 * HH * 4;         // 64 KB
    float* cseed = (float*)(ws + off); off += (size_t)NGRP * 8 * HH * 4;         // 64 KB
    const size_t clear_bytes = off;
    float* out1 = (float*)(ws + off); off += (size_t)TT * BB * 2 * HH * 4;       // 128 MB

    // acc (atomic target), packet buffers (tag space), seeds: zero each launch
    hipMemsetAsync(d_ws, 0, clear_bytes, stream);

    // layer 1: x (B,T,D)
    lstm_scan<DD, 1><<<NGRP * NRANK, NTH, 0, stream>>>(
        x, (long)TT * DD, (long)DD,
        wih1f, whh1f, bih1f, bhh1f, wih1r, whh1r, bih1r, bhh1r,
        hseed, cseed, hbt1, out1, nullptr, nullptr, 0);

    // layer 2: out1 (T,B,2H); seeds = layer-1 finals
    lstm_scan<2 * HH, 2><<<NGRP * NRANK, NTH, 0, stream>>>(
        out1, (long)(2 * HH), (long)(BB * 2 * HH),
        wih2f, whh2f, bih2f, bhh2f, wih2r, whh2r, bih2r, bhh2r,
        hseed, cseed, hbt2, nullptr, acc, fcw, 0);

    finalize_k<<<(BB * TT + 255) / 256, 256, 0, stream>>>(acc, fcb, (float*)d_out);
}

// Round 13
// 13018.330 us; speedup vs baseline: 1.6089x; 1.1593x over previous
//
#include <hip/hip_runtime.h>

#define BB 32      // batch
#define TT 2048    // time steps
#define DD 128     // input dim (layer 1)
#define HH 256     // hidden
#define NTH 512    // threads per block (8 waves -> 2 waves/SIMD)
#define NRANK 32   // blocks (ranks) per group
#define NGRP 8     // groups = 2 dirs x 4 batch-quads
#define HASHK 2654435761u

typedef float f32x4 __attribute__((ext_vector_type(4)));
typedef unsigned int u32;
typedef u32 u32x2 __attribute__((ext_vector_type(2)));
typedef u32 u32x4 __attribute__((ext_vector_type(4)));
typedef _Float16 f16;
typedef f16 f16x2 __attribute__((ext_vector_type(2)));
typedef f16 f16x4 __attribute__((ext_vector_type(4)));

#if defined(__has_builtin)
#if __has_builtin(__builtin_amdgcn_fdot2)
#define FDOT2(a, b, c) __builtin_amdgcn_fdot2((a), (b), (c), false)
#endif
#endif
#ifndef FDOT2
#define FDOT2(a, b, c) ((c) + (float)(a)[0] * (float)(b)[0] + (float)(a)[1] * (float)(b)[1])
#endif

__device__ __forceinline__ float sigm(float x)  { return 1.0f / (1.0f + __expf(-x)); }
__device__ __forceinline__ float tanh_f(float x){ return 1.0f - 2.0f / (__expf(2.0f * x) + 1.0f); }

// Persistent bidirectional scan; 256 blocks = 8 groups x 32 ranks, 1 block/CU.
// == The 10.45ms r7 winner (spin issued AFTER x-dot; its vmcnt(0) draining px
// is a LOAD-BEARING delay before the first tag check -- r8/r12 lessons), with
// ONE change: the dots use f16 packed v_dot2 (f16 inputs, f32 accumulate).
// W in registers as f16x2 pairs (48 VGPR, was 96); z staged in LDS as f16
// (ds_read_b64, ~half the LDS-pipe time). State, exchange packets (h fp32 +
// tag), red2 reduction, and cell math remain fp32.
template<int KIN, int LAYER>
__global__ __launch_bounds__(NTH, 1)
void lstm_scan(const float* __restrict__ in_seq, long sb, long st,
               const float* __restrict__ wih_f, const float* __restrict__ whh_f,
               const float* __restrict__ bih_f, const float* __restrict__ bhh_f,
               const float* __restrict__ wih_r, const float* __restrict__ whh_r,
               const float* __restrict__ bih_r, const float* __restrict__ bhh_r,
               float* __restrict__ hseed,      // [NGRP][8][HH]
               float* __restrict__ cseed,      // [NGRP][8][HH]
               u32* __restrict__ hbt,          // [NGRP][2par][256j][8b][2]
               float* __restrict__ out1,       // [TT][BB][2H]
               float* __restrict__ acc,        // [TT][BB]
               const float* __restrict__ fcw,  // [2H]
               int never)
{
    constexpr int KINP = KIN + 4;   // zx stride in f16 elems; row = (KIN+4)*2 B, 8B-aligned
    constexpr int HHP  = HH + 4;    // zh stride: 520 B rows
    constexpr int C4   = KIN / 4;
    constexpr int XC   = KIN / 128;                  // x chunks (1 / 4)
    constexpr int NPXI = (8 * C4 + NTH - 1) / NTH;   // px f32x4/thread (1 / 2)
    constexpr int RSTR = 36;                         // red2 stride (floats)
    constexpr int PADN = (LAYER == 1) ? 9600 : 8192; // LDS > 80KB: 1 blk/CU

    const int blk  = blockIdx.x;
    const int g    = blk & 7;
    const int rank = blk >> 3;
    const int dir  = g & 1;
    const int bq   = g >> 1;
    const int tid  = threadIdx.x;

    __shared__ __align__(16) f16 zx[8][KINP];
    __shared__ __align__(16) f16 zh[8][HHP];
    __shared__ __align__(16) float red2[256 * RSTR];
    __shared__ float gates_s[4][8][9];
    __shared__ float bias_s[32];
    __shared__ float padlds[PADN];
    if (never) padlds[never & (PADN - 1)] = 1.0f;

    const float* wih = dir ? wih_r : wih_f;
    const float* whh = dir ? whh_r : whh_f;
    const float* bih = dir ? bih_r : bih_f;
    const float* bhh = dir ? bhh_r : bhh_f;

    // dot roles: thread = (bh, rg, sl): rows rg*4..+3, b = bh*4..+3, k-slice sl
    const int bh = tid >> 8;        // 0/1
    const int rg = (tid >> 5) & 7;  // 0..7
    const int sl = tid & 31;        // 0..31

    // ---- one-time: W slice -> REGISTERS as f16x2 pairs ----
    f16x2 wxp[4][XC][2], whp[4][2][2];
    #pragma unroll
    for (int rr = 0; rr < 4; ++rr) {
        const int r = rg * 4 + rr;
        const int grow = (r >> 3) * HH + rank * 8 + (r & 7);
        #pragma unroll
        for (int c = 0; c < XC; ++c) {
            const f32x4 wv = *(const f32x4*)(wih + (long)grow * KIN + sl * 4 + 128 * c);
            f16x2 lo, hi;
            lo[0] = (f16)wv.x; lo[1] = (f16)wv.y;
            hi[0] = (f16)wv.z; hi[1] = (f16)wv.w;
            wxp[rr][c][0] = lo; wxp[rr][c][1] = hi;
        }
        #pragma unroll
        for (int c = 0; c < 2; ++c) {
            const f32x4 wv = *(const f32x4*)(whh + (long)grow * HH + sl * 4 + 128 * c);
            f16x2 lo, hi;
            lo[0] = (f16)wv.x; lo[1] = (f16)wv.y;
            hi[0] = (f16)wv.z; hi[1] = (f16)wv.w;
            whp[rr][c][0] = lo; whp[rr][c][1] = hi;
        }
    }
    if (tid < 32) {
        const int grow = (tid >> 3) * HH + rank * 8 + (tid & 7);
        bias_s[tid] = bih[grow] + bhh[grow];
    }

    u32* hbt_g = hbt + g * (2 * 256 * 8 * 2);
    float* hs_seed = hseed + g * (8 * HH);
    float* cs_seed = cseed + g * (8 * HH);

    // update roles (tid < 64)
    const int jj2   = tid >> 3;
    const int bl2   = tid & 7;
    const int jglob = rank * 8 + jj2;

    float creg = 0.0f, fcv = 0.0f;
    if (tid < 64 && LAYER == 2) {
        creg = cs_seed[bl2 * HH + jglob];
        fcv  = fcw[dir * HH + jglob];
    }

    // ---- prolog: zx (f16) for s=0; seed packets (tag 1, h fp32) ----
    {
        const int t0 = dir ? (TT - 1) : 0;
        const long tb = (long)t0 * st;
        for (int q = tid; q < 8 * C4; q += NTH) {
            const int bl = q / C4;
            const int k4 = q - bl * C4;
            const f32x4 v = *(const f32x4*)(in_seq + (long)(bq * 8 + bl) * sb + tb + k4 * 4);
            f16x4 h4;
            h4[0] = (f16)v.x; h4[1] = (f16)v.y; h4[2] = (f16)v.z; h4[3] = (f16)v.w;
            *(f16x4*)&zx[bl][k4 * 4] = h4;
        }
        if (tid < 64) {
            const float h0 = (LAYER == 1) ? 0.0f : hs_seed[bl2 * HH + jglob];
            const u32 hx = __float_as_uint(h0);
            u32x2 pkt; pkt.x = hx; pkt.y = 1u + hx * HASHK;
            u32* pp = hbt_g + ((0 * 256 + jglob) * 8 + bl2) * 2;
            asm volatile("global_store_dwordx2 %0, %1, off sc0 sc1"
                         :: "v"(pp), "v"(pkt) : "memory");
        }
    }
    __syncthreads();

    for (int s = 0; s < TT; ++s) {
        const int t = dir ? (TT - 1 - s) : s;

        // ---- P0: prefetch x slice for step s+1 (fp32 regs; staged in P3) ----
        f32x4 px[NPXI];
        if (s + 1 < TT) {
            const long tb = (long)(dir ? (t - 1) : (t + 1)) * st;
            #pragma unroll
            for (int i = 0; i < NPXI; ++i) {
                const int q = tid + i * NTH;
                if (q < 8 * C4) {
                    const int bl = q / C4;
                    const int k4 = q - bl * C4;
                    px[i] = *(const f32x4*)(in_seq + (long)(bq * 8 + bl) * sb + tb + k4 * 4);
                }
            }
        }

        // ---- P1: x-part of dot (W f16x2 in regs, z f16 from LDS) ----
        float ac[4][4];
        #pragma unroll
        for (int rr = 0; rr < 4; ++rr)
            #pragma unroll
            for (int b = 0; b < 4; ++b) ac[rr][b] = 0.0f;
        #pragma unroll
        for (int c = 0; c < XC; ++c) {
            f16x2 zlo[4], zhi[4];
            #pragma unroll
            for (int b = 0; b < 4; ++b) {
                const f16x4 zv = *(const f16x4*)&zx[bh * 4 + b][sl * 4 + 128 * c];
                zlo[b] = __builtin_shufflevector(zv, zv, 0, 1);
                zhi[b] = __builtin_shufflevector(zv, zv, 2, 3);
            }
            #pragma unroll
            for (int rr = 0; rr < 4; ++rr)
                #pragma unroll
                for (int b = 0; b < 4; ++b) {
                    ac[rr][b] = FDOT2(wxp[rr][c][0], zlo[b], ac[rr][b]);
                    ac[rr][b] = FDOT2(wxp[rr][c][1], zhi[b], ac[rr][b]);
                }
        }

        // ---- P2: spin-load tagged h packets (tid<256: thread owns j=tid) ----
        // (vmcnt(0) also drains px: that delay is load-bearing, see r8/r12)
        if (tid < 256) {
            const u32 tg = (u32)(s + 1);
            const u32* hp = hbt_g + (((s & 1) * 256 + tid) * 8) * 2;
            u32x4 q0, q1, q2, q3;
            while (true) {
                asm volatile(
                    "global_load_dwordx4 %0, %4, off sc0 sc1\n\t"
                    "global_load_dwordx4 %1, %4, off offset:16 sc0 sc1\n\t"
                    "global_load_dwordx4 %2, %4, off offset:32 sc0 sc1\n\t"
                    "global_load_dwordx4 %3, %4, off offset:48 sc0 sc1\n\t"
                    "s_waitcnt vmcnt(0)"
                    : "=&v"(q0), "=&v"(q1), "=&v"(q2), "=&v"(q3)
                    : "v"(hp) : "memory");
                const bool ok =
                    (q0.y - q0.x * HASHK == tg) && (q0.w - q0.z * HASHK == tg) &&
                    (q1.y - q1.x * HASHK == tg) && (q1.w - q1.z * HASHK == tg) &&
                    (q2.y - q2.x * HASHK == tg) && (q2.w - q2.z * HASHK == tg) &&
                    (q3.y - q3.x * HASHK == tg) && (q3.w - q3.z * HASHK == tg);
                if (ok) break;
                __builtin_amdgcn_s_sleep(1);
            }
            zh[0][tid] = (f16)__uint_as_float(q0.x);
            zh[1][tid] = (f16)__uint_as_float(q0.z);
            zh[2][tid] = (f16)__uint_as_float(q1.x);
            zh[3][tid] = (f16)__uint_as_float(q1.z);
            zh[4][tid] = (f16)__uint_as_float(q2.x);
            zh[5][tid] = (f16)__uint_as_float(q2.z);
            zh[6][tid] = (f16)__uint_as_float(q3.x);
            zh[7][tid] = (f16)__uint_as_float(q3.z);
        }
        __syncthreads();   // B1: zh ready; zx(s) reads complete

        // ---- P3: h-part of dot + red2 partial writes; stage px -> zx ----
        #pragma unroll
        for (int c = 0; c < 2; ++c) {
            f16x2 zlo[4], zhi[4];
            #pragma unroll
            for (int b = 0; b < 4; ++b) {
                const f16x4 zv = *(const f16x4*)&zh[bh * 4 + b][sl * 4 + 128 * c];
                zlo[b] = __builtin_shufflevector(zv, zv, 0, 1);
                zhi[b] = __builtin_shufflevector(zv, zv, 2, 3);
            }
            #pragma unroll
            for (int rr = 0; rr < 4; ++rr)
                #pragma unroll
                for (int b = 0; b < 4; ++b) {
                    ac[rr][b] = FDOT2(whp[rr][c][0], zlo[b], ac[rr][b]);
                    ac[rr][b] = FDOT2(whp[rr][c][1], zhi[b], ac[rr][b]);
                }
        }
        #pragma unroll
        for (int rr = 0; rr < 4; ++rr)
            #pragma unroll
            for (int b = 0; b < 4; ++b)
                red2[((rg * 4 + rr) * 8 + bh * 4 + b) * RSTR + sl] = ac[rr][b];
        if (s + 1 < TT) {
            #pragma unroll
            for (int i = 0; i < NPXI; ++i) {
                const int q = tid + i * NTH;
                if (q < 8 * C4) {
                    const int bl = q / C4;
                    const int k4 = q - bl * C4;
                    f16x4 h4;
                    h4[0] = (f16)px[i].x; h4[1] = (f16)px[i].y;
                    h4[2] = (f16)px[i].z; h4[3] = (f16)px[i].w;
                    *(f16x4*)&zx[bl][k4 * 4] = h4;
                }
            }
        }
        __syncthreads();   // B2: red2 + new zx ready

        // ---- P4: reduce 32 k-slices -> gate pre-activations (tid<256) ----
        if (tid < 256) {
            float sg = bias_s[tid >> 3];
            const f32x4* rp = (const f32x4*)&red2[tid * RSTR];
            #pragma unroll
            for (int q = 0; q < 8; ++q) {
                const f32x4 v = rp[q];
                sg += v.x + v.y + v.z + v.w;
            }
            gates_s[tid >> 6][(tid >> 3) & 7][tid & 7] = sg;
        }
        __syncthreads();   // B3: gates ready

        // ---- P5: cell update; packet store FIRST, then outputs ----
        if (tid < 64) {
            const float gi = gates_s[0][jj2][bl2];
            const float gf = gates_s[1][jj2][bl2];
            const float gg = gates_s[2][jj2][bl2];
            const float go = gates_s[3][jj2][bl2];
            creg = sigm(gf) * creg + sigm(gi) * tanh_f(gg);
            const float hv = sigm(go) * tanh_f(creg);
            if (s + 1 < TT) {
                const u32 hx = __float_as_uint(hv);
                u32x2 pkt; pkt.x = hx; pkt.y = (u32)(s + 2) + hx * HASHK;
                u32* pp = hbt_g + ((((s + 1) & 1) * 256 + jglob) * 8 + bl2) * 2;
                asm volatile("global_store_dwordx2 %0, %1, off sc0 sc1"
                             :: "v"(pp), "v"(pkt) : "memory");
            }
            if (LAYER == 1) {
                out1[(long)t * (BB * 2 * HH) + (bq * 8 + bl2) * (2 * HH) + dir * HH + jglob] = hv;
                if (s == TT - 1) {
                    hs_seed[bl2 * HH + jglob] = hv;
                    cs_seed[bl2 * HH + jglob] = creg;
                }
            } else {
                float val = hv * fcv;
                val += __shfl_down(val, 32, 64);
                val += __shfl_down(val, 16, 64);
                val += __shfl_down(val, 8, 64);
                if (jj2 == 0) atomicAdd(&acc[t * BB + bq * 8 + bl2], val);
            }
        }
    }
}

__global__ void finalize_k(const float* __restrict__ acc, const float* __restrict__ fcb,
                           float* __restrict__ out)
{
    const int i = blockIdx.x * blockDim.x + threadIdx.x;
    if (i < BB * TT) {
        const int b = i >> 11;
        const int t = i & (TT - 1);
        out[i] = tanhf(acc[t * BB + b] + fcb[0]);
    }
}

extern "C" void kernel_launch(void* const* d_in, const int* in_sizes, int n_in,
                              void* d_out, int out_size, void* d_ws, size_t ws_size,
                              hipStream_t stream) {
    const float* x     = (const float*)d_in[0];
    const float* wih1f = (const float*)d_in[1];
    const float* whh1f = (const float*)d_in[2];
    const float* bih1f = (const float*)d_in[3];
    const float* bhh1f = (const float*)d_in[4];
    const float* wih1r = (const float*)d_in[5];
    const float* whh1r = (const float*)d_in[6];
    const float* bih1r = (const float*)d_in[7];
    const float* bhh1r = (const float*)d_in[8];
    const float* wih2f = (const float*)d_in[9];
    const float* whh2f = (const float*)d_in[10];
    const float* bih2f = (const float*)d_in[11];
    const float* bhh2f = (const float*)d_in[12];
    const float* wih2r = (const float*)d_in[13];
    const float* whh2r = (const float*)d_in[14];
    const float* bih2r = (const float*)d_in[15];
    const float* bhh2r = (const float*)d_in[16];
    const float* fcw   = (const float*)d_in[17];
    const float* fcb   = (const float*)d_in[18];

    char* ws = (char*)d_ws;
    size_t off = 0;
    float* acc  = (float*)(ws + off); off += (size_t)TT * BB * 4;                // 256 KB
    u32* hbt1   = (u32*)(ws + off);   off += (size_t)NGRP * 2 * 256 * 8 * 2 * 4; // 256 KB
    u32* hbt2   = (u32*)(ws + off);   off += (size_t)NGRP * 2 * 256 * 8 * 2 * 4; // 256 KB
    float* hseed = (float*)(ws + off); off += (size_t)NGRP * 8 * HH * 4;         // 64 KB
    float* cseed = (float*)(ws + off); off += (size_t)NGRP * 8 * HH * 4;         // 64 KB
    const size_t clear_bytes = off;
    float* out1 = (float*)(ws + off); off += (size_t)TT * BB * 2 * HH * 4;       // 128 MB

    // acc (atomic target), packet buffers (tag space), seeds: zero each launch
    hipMemsetAsync(d_ws, 0, clear_bytes, stream);

    // layer 1: x (B,T,D)
    lstm_scan<DD, 1><<<NGRP * NRANK, NTH, 0, stream>>>(
        x, (long)TT * DD, (long)DD,
        wih1f, whh1f, bih1f, bhh1f, wih1r, whh1r, bih1r, bhh1r,
        hseed, cseed, hbt1, out1, nullptr, nullptr, 0);

    // layer 2: out1 (T,B,2H); seeds = layer-1 finals
    lstm_scan<2 * HH, 2><<<NGRP * NRANK, NTH, 0, stream>>>(
        out1, (long)(2 * HH), (long)(BB * 2 * HH),
        wih2f, whh2f, bih2f, bhh2f, wih2r, whh2r, bih2r, bhh2r,
        hseed, cseed, hbt2, nullptr, acc, fcw, 0);

    finalize_k<<<(BB * TT + 255) / 256, 256, 0, stream>>>(acc, fcb, (float*)d_out);
}